// Round 2
// baseline (10.344 us; speedup 1.0000x reference)
//
#include <hip/hip_runtime.h>

#define W     16      // CHUNK
#define TILE  1024    // outputs per block
#define NTHR  256     // threads per block

// out[b,t] = E[t] * sum_{k=0..15} emit[t+k] / S[t+k]
//   E[j] = exp(logits[j])          (E=0 outside [0,T) -- matches -FMAX pad)
//   S[u] = sum_{j=u-15..u} E[j]
//   g[u] = emit[u]/S[u] for u<T else 0   (matches 0-prob / FMAX-denom pad)
__global__ __launch_bounds__(NTHR)
void mocha_chunkwise_kernel(const float* __restrict__ emit,
                            const float* __restrict__ logits,
                            float* __restrict__ out,
                            int T)
{
    const int b   = blockIdx.y;
    const int t0  = blockIdx.x * TILE;
    const int tid = threadIdx.x;

    const float* lrow = logits + (size_t)b * T;
    const float* erow = emit   + (size_t)b * T;
    float*       orow = out    + (size_t)b * T;

    // Es[i] = E[t0 - 16 + i], i in [0, 1056)
    __shared__ float Es[TILE + 2 * W];       // 1056 floats
    // Gs[i] = g[t0 + i],      i in [0, 1040)  (1039 used)
    __shared__ float Gs[TILE + W];           // 1040 floats

    // ---- phase 1: stage E = exp(logits) into LDS, float4-vectorized ----
    #pragma unroll
    for (int c = tid; c < (TILE + 2 * W) / 4; c += NTHR) {   // 264 chunks
        const int i = 4 * c;
        const int j = t0 - W + i;                            // global index of Es[i]
        float4 v;
        if (j >= 0 && j + 3 < T) {
            v = *reinterpret_cast<const float4*>(lrow + j);
            v.x = __expf(v.x); v.y = __expf(v.y);
            v.z = __expf(v.z); v.w = __expf(v.w);
        } else {
            float tv[4];
            #pragma unroll
            for (int e = 0; e < 4; ++e) {
                const int jj = j + e;
                tv[e] = (jj >= 0 && jj < T) ? __expf(lrow[jj]) : 0.0f;
            }
            v.x = tv[0]; v.y = tv[1]; v.z = tv[2]; v.w = tv[3];
        }
        *reinterpret_cast<float4*>(Es + i) = v;
    }
    __syncthreads();

    // ---- phase 2: Gs[i] = emit[u] / S[u], 4 positions per thread ----
    #pragma unroll
    for (int c = tid; c < (TILE + W) / 4; c += NTHR) {       // 260 chunks
        const int i = 4 * c;
        const int u = t0 + i;

        float e[20];                                          // Es[i .. i+19]
        #pragma unroll
        for (int q = 0; q < 5; ++q) {
            float4 v = *reinterpret_cast<const float4*>(Es + i + 4 * q);
            e[4*q+0] = v.x; e[4*q+1] = v.y; e[4*q+2] = v.z; e[4*q+3] = v.w;
        }

        float em[4];
        if (u + 3 < T) {
            float4 v = *reinterpret_cast<const float4*>(erow + u);
            em[0] = v.x; em[1] = v.y; em[2] = v.z; em[3] = v.w;
        } else {
            #pragma unroll
            for (int e2 = 0; e2 < 4; ++e2)
                em[e2] = (u + e2 < T) ? erow[u + e2] : 0.0f;
        }

        float gv[4];
        #pragma unroll
        for (int r = 0; r < 4; ++r) {
            // S[u+r] = sum E[u+r-15 .. u+r] = sum Es[i+r+1 .. i+r+16]
            float S = 0.0f;
            #pragma unroll
            for (int k = 1; k <= W; ++k) S += e[k + r];
            gv[r] = (u + r < T) ? __fdividef(em[r], S) : 0.0f;
        }
        float4 g4 = make_float4(gv[0], gv[1], gv[2], gv[3]);
        *reinterpret_cast<float4*>(Gs + i) = g4;
    }
    __syncthreads();

    // ---- phase 3: sliding 16-sum of G, scale by E[t], float4 store ----
    {
        const int i = 4 * tid;                                // output chunk offset
        const int t = t0 + i;

        float g[20];                                          // Gs[i .. i+19] (19 used)
        #pragma unroll
        for (int q = 0; q < 5; ++q) {
            float4 v = *reinterpret_cast<const float4*>(Gs + i + 4 * q);
            g[4*q+0] = v.x; g[4*q+1] = v.y; g[4*q+2] = v.z; g[4*q+3] = v.w;
        }
        float4 myE = *reinterpret_cast<const float4*>(Es + i + W);  // E[t..t+3]
        const float eArr[4] = {myE.x, myE.y, myE.z, myE.w};

        float res[4];
        #pragma unroll
        for (int r = 0; r < 4; ++r) {
            float acc = 0.0f;
            #pragma unroll
            for (int k = 0; k < W; ++k) acc += g[r + k];
            res[r] = eArr[r] * acc;
        }

        if (t + 3 < T) {
            *reinterpret_cast<float4*>(orow + t) =
                make_float4(res[0], res[1], res[2], res[3]);
        } else {
            #pragma unroll
            for (int r = 0; r < 4; ++r)
                if (t + r < T) orow[t + r] = res[r];
        }
    }
}

extern "C" void kernel_launch(void* const* d_in, const int* in_sizes, int n_in,
                              void* d_out, int out_size, void* d_ws, size_t ws_size,
                              hipStream_t stream)
{
    const float* emit   = (const float*)d_in[0];   // emit_probs     [B,T]
    const float* logits = (const float*)d_in[1];   // softmax_logits [B,T]
    float*       out    = (float*)d_out;           // [B,T] fp32

    const int T = 16384;
    const int B = in_sizes[0] / T;                 // 64

    dim3 grid(T / TILE, B);                        // 16 x 64 = 1024 blocks
    dim3 block(NTHR);
    mocha_chunkwise_kernel<<<grid, block, 0, stream>>>(emit, logits, out, T);
}